// Round 17
// baseline (144.591 us; speedup 1.0000x reference)
//
#include <hip/hip_runtime.h>
#include <stdint.h>

// LocalAttention: x[2,2048,1024] -> QKV proj -> anti-local attention (keep |i-j|>16) -> out proj.
// Round 17: r16 (32x32x16 MFMA attention) + the missing PAIR reductions: a q-row's 64 scores
// live in lanes (q,hi=0) and (q,hi=1); pm must be merged across the pair (1x shfl_xor 32 per
// tile) and lsum merged once in the epilogue. r16's per-lane m/lsum split the row -> 7e-2 error.

typedef unsigned short u16;
typedef short bf16x8 __attribute__((ext_vector_type(8)));
typedef float f32x4 __attribute__((ext_vector_type(4)));
typedef float f32x16 __attribute__((ext_vector_type(16)));

#define MFMA16 __builtin_amdgcn_mfma_f32_16x16x32_bf16
#define MFMA32 __builtin_amdgcn_mfma_f32_32x32x16_bf16

__device__ __forceinline__ u16 f2bf(float f) {
  union { float f; uint32_t u; } v; v.f = f;
  return (u16)((v.u + 0x7fffu + ((v.u >> 16) & 1u)) >> 16);
}

__device__ __forceinline__ uint32_t cvt_pk_bf16(float lo, float hi) {
  uint32_t d;
  asm("v_cvt_pk_bf16_f32 %0, %1, %2" : "=v"(d) : "v"(lo), "v"(hi));
  return d;
}

// raw hardware exp2 (v_exp_f32 IS exp2 on gfx950; no libm guard code)
__device__ __forceinline__ float hexp2(float x) {
  float r;
  asm("v_exp_f32 %0, %1" : "=v"(r) : "v"(x));
  return r;
}

// ---------------- fp32 -> bf16 conversion ----------------
__global__ void f2b_kernel(const float* __restrict__ in, u16* __restrict__ out, int n4) {
  int i = blockIdx.x * blockDim.x + threadIdx.x;
  if (i < n4) {
    float4 v = reinterpret_cast<const float4*>(in)[i];
    ushort4 o;
    o.x = f2bf(v.x); o.y = f2bf(v.y); o.z = f2bf(v.z); o.w = f2bf(v.w);
    reinterpret_cast<ushort4*>(out)[i] = o;
  }
}

__global__ void f2b4_kernel(const float* __restrict__ a, const float* __restrict__ b,
                            const float* __restrict__ c, const float* __restrict__ d,
                            u16* __restrict__ oa, u16* __restrict__ ob,
                            u16* __restrict__ oc, u16* __restrict__ od, int n4) {
  int i = blockIdx.x * blockDim.x + threadIdx.x;
  if (i >= n4) return;
  int w = blockIdx.y;
  const float* src = (w == 0) ? a : (w == 1) ? b : (w == 2) ? c : d;
  u16* dst = (w == 0) ? oa : (w == 1) ? ob : (w == 2) ? oc : od;
  float4 v = reinterpret_cast<const float4*>(src)[i];
  ushort4 o;
  o.x = f2bf(v.x); o.y = f2bf(v.y); o.z = f2bf(v.z); o.w = f2bf(v.w);
  reinterpret_cast<ushort4*>(dst)[i] = o;
}

// ---------------- shared GEMM core (padded LDS, reg-staged, NAMED registers) ----------------
#define GEMM_LOAD(REGA, REGB, A_, B_, KOFF)                                                        \
  do {                                                                                             \
    REGA##0 = *reinterpret_cast<const uint4*>(A_ + (size_t)(gm_base +  0) * 1024 + (KOFF) + sslot * 8); \
    REGA##1 = *reinterpret_cast<const uint4*>(A_ + (size_t)(gm_base + 32) * 1024 + (KOFF) + sslot * 8); \
    REGA##2 = *reinterpret_cast<const uint4*>(A_ + (size_t)(gm_base + 64) * 1024 + (KOFF) + sslot * 8); \
    REGA##3 = *reinterpret_cast<const uint4*>(A_ + (size_t)(gm_base + 96) * 1024 + (KOFF) + sslot * 8); \
    REGB##0 = *reinterpret_cast<const uint4*>(B_ + (size_t)(gn_base +  0) * 1024 + (KOFF) + sslot * 8); \
    REGB##1 = *reinterpret_cast<const uint4*>(B_ + (size_t)(gn_base + 32) * 1024 + (KOFF) + sslot * 8); \
    REGB##2 = *reinterpret_cast<const uint4*>(B_ + (size_t)(gn_base + 64) * 1024 + (KOFF) + sslot * 8); \
    REGB##3 = *reinterpret_cast<const uint4*>(B_ + (size_t)(gn_base + 96) * 1024 + (KOFF) + sslot * 8); \
  } while (0)

#define GEMM_PUBLISH()                                                                             \
  do {                                                                                             \
    *reinterpret_cast<uint4*>((char*)As + (srow +  0) * 144 + sslot * 16) = ar0;                   \
    *reinterpret_cast<uint4*>((char*)As + (srow + 32) * 144 + sslot * 16) = ar1;                   \
    *reinterpret_cast<uint4*>((char*)As + (srow + 64) * 144 + sslot * 16) = ar2;                   \
    *reinterpret_cast<uint4*>((char*)As + (srow + 96) * 144 + sslot * 16) = ar3;                   \
    *reinterpret_cast<uint4*>((char*)Bs + (srow +  0) * 144 + sslot * 16) = br0;                   \
    *reinterpret_cast<uint4*>((char*)Bs + (srow + 32) * 144 + sslot * 16) = br1;                   \
    *reinterpret_cast<uint4*>((char*)Bs + (srow + 64) * 144 + sslot * 16) = br2;                   \
    *reinterpret_cast<uint4*>((char*)Bs + (srow + 96) * 144 + sslot * 16) = br3;                   \
  } while (0)

#define GEMM_CORE(A_, B_, bm0_, bn0_)                                                              \
  constexpr int KP = 72;                                                                           \
  __shared__ __align__(16) u16 As[128 * KP];                                                       \
  __shared__ __align__(16) u16 Bs[128 * KP];                                                       \
  const int t = threadIdx.x;                                                                       \
  const int lane = t & 63;                                                                         \
  const int wv = t >> 6;                                                                           \
  const int wm = (wv >> 1) * 64;                                                                   \
  const int wn = (wv & 1) * 64;                                                                    \
  const int lg = lane >> 4;                                                                        \
  const int lr = lane & 15;                                                                        \
  const int srow = t >> 3;                                                                         \
  const int sslot = t & 7;                                                                         \
  const int gm_base = bm0_ + srow;                                                                 \
  const int gn_base = bn0_ + srow;                                                                 \
  uint4 ar0, ar1, ar2, ar3, br0, br1, br2, br3;                                                    \
  f32x4 acc[4][4];                                                                                 \
  for (int i = 0; i < 4; ++i)                                                                      \
    for (int j = 0; j < 4; ++j) acc[i][j] = (f32x4)0.0f;                                           \
  GEMM_LOAD(ar, br, A_, B_, 0);                                                                    \
  for (int k0 = 0; k0 < 1024; k0 += 64) {                                                          \
    GEMM_PUBLISH();                                                                                \
    __syncthreads();                                                                               \
    if (k0 + 64 < 1024) GEMM_LOAD(ar, br, A_, B_, k0 + 64);                                        \
    for (int kk = 0; kk < 2; ++kk) {                                                               \
      bf16x8 af[4], bfr[4];                                                                        \
      for (int i = 0; i < 4; ++i)                                                                  \
        af[i] = *reinterpret_cast<const bf16x8*>(&As[(wm + i * 16 + lr) * KP + kk * 32 + lg * 8]); \
      for (int j = 0; j < 4; ++j)                                                                  \
        bfr[j] = *reinterpret_cast<const bf16x8*>(&Bs[(wn + j * 16 + lr) * KP + kk * 32 + lg * 8]);\
      for (int i = 0; i < 4; ++i)                                                                  \
        for (int j = 0; j < 4; ++j)                                                                \
          acc[i][j] = MFMA16(af[i], bfr[j], acc[i][j], 0, 0, 0);                                   \
    }                                                                                              \
    __syncthreads();                                                                               \
  }

// ---------------- fused QKV GEMM ----------------
__global__ __launch_bounds__(256) void gemm_qkv(
    const u16* __restrict__ A,
    const u16* __restrict__ Wqb, const u16* __restrict__ Wkb, const u16* __restrict__ Wvb,
    const float* __restrict__ bqp, const float* __restrict__ bkp, const float* __restrict__ bvp,
    u16* __restrict__ qo, u16* __restrict__ ko, u16* __restrict__ vo)
{
  const int bid = blockIdx.x + gridDim.x * blockIdx.y;
  const int sid = (bid & 7) * 96 + (bid >> 3);
  const int bm0 = (sid / 24) * 128;
  const int jy = sid % 24;
  const int sel = jy >> 3;
  const int bn0 = (jy & 7) * 128;

  const u16* Bw = (sel == 0) ? Wqb : (sel == 1) ? Wkb : Wvb;
  const float* bias = (sel == 0) ? bqp : (sel == 1) ? bkp : bvp;
  // Q scale folds softmax 1/8 AND log2(e) (exp2-domain softmax downstream)
  const float scale = (sel == 0) ? 0.125f * 1.44269504f : 1.0f;

  GEMM_CORE(A, Bw, bm0, bn0)

  for (int j = 0; j < 4; ++j) {
    int gn = bn0 + wn + j * 16 + lr;
    float bv = bias[gn];
    for (int i = 0; i < 4; ++i) {
      for (int r = 0; r < 4; ++r) {
        int gm = bm0 + wm + i * 16 + lg * 4 + r;
        float val = (acc[i][j][r] + bv) * scale;
        int b = gm >> 11, tt = gm & 2047;
        int h = gn >> 6,  d = gn & 63;
        u16 o = f2bf(val);
        if (sel == 0)
          qo[((size_t)(b * 16 + h) * 2048 + tt) * 64 + d] = o;
        else if (sel == 1)
          ko[((size_t)(b * 16 + h) * 2048 + tt) * 64 + d] = o;
        else
          vo[((size_t)(b * 16 + h) * 64 + d) * 2048 + tt] = o;
      }
    }
  }
}

// ---------------- out-proj GEMM: C[M,N] fp32 = A @ W^T + bias ----------------
__global__ __launch_bounds__(256) void gemm_out(
    const u16* __restrict__ A, const u16* __restrict__ Bw,
    const float* __restrict__ bias, float* __restrict__ outp)
{
  const int bm0 = blockIdx.x * 128;
  const int bn0 = blockIdx.y * 128;

  GEMM_CORE(A, Bw, bm0, bn0)

  for (int j = 0; j < 4; ++j) {
    int gn = bn0 + wn + j * 16 + lr;
    float bv = bias[gn];
    for (int i = 0; i < 4; ++i)
      for (int r = 0; r < 4; ++r) {
        int gm = bm0 + wm + i * 16 + lg * 4 + r;
        outp[(size_t)gm * 1024 + gn] = acc[i][j][r] + bv;
      }
  }
}

// ---------------- attention (32x32x16 MFMA, pair-reduced softmax) ----------------
// grid 512 blocks remapped XCD-aware. Block: 4 waves, 128 q-rows; wave owns 32 q-rows.
// Swapped QK^T via MFMA32: D col = lane&31 = q. Row q's 64 keys split across the lane PAIR
// (q,hi=0)/(q,hi=1): pm needs ONE shfl_xor(32) per tile; m then identical within the pair,
// so P is consistent; lsum pair-merged once in epilogue. (r16 bug: per-lane m/lsum split rows.)
// C/D: col=lane&31, row=(reg&3)+8*(reg>>2)+4*(lane>>5). K/V/P LDS rows padded to 72 u16.
__global__ __launch_bounds__(256) void attn_kernel(
    const u16* __restrict__ qb, const u16* __restrict__ kb,
    const u16* __restrict__ vtb, u16* __restrict__ ab)
{
  constexpr int KP = 72;
  __shared__ __align__(16) u16 Kb[2][64 * KP];
  __shared__ __align__(16) u16 Vb[2][64 * KP];
  __shared__ __align__(16) u16 Pl[4][32 * KP];

  const int bid = blockIdx.x + gridDim.x * blockIdx.y;
  const int sid = (bid & 7) * 64 + (bid >> 3);
  const int bx = sid & 15;
  const int bh = sid >> 4;                   // b*16+h

  const int t = threadIdx.x;
  const int lane = t & 63;
  const int wv = t >> 6;
  const int ql = lane & 31;                  // this lane's q-row (within wave tile)
  const int hi = lane >> 5;                  // k-half / key-half selector
  const int q0 = bx * 128 + wv * 32;

  const u16* Qp = qb + (size_t)bh * 2048 * 64;
  const u16* Kp = kb + (size_t)bh * 2048 * 64;
  const u16* Vt = vtb + (size_t)bh * 64 * 2048;
  char* Pw = (char*)&Pl[wv][0];

  const int sl = lane & 7;
  const int r0 = wv * 16 + (lane >> 3);
  const int sdst0 = r0 * (KP * 2) + sl * 16;

  uint4 krA, krB, vrA, vrB;

#define ISSUE_LOADS(J0N)                                                                 \
  do {                                                                                   \
    krA = *reinterpret_cast<const uint4*>(Kp + (size_t)((J0N) + r0) * 64 + sl * 8);      \
    krB = *reinterpret_cast<const uint4*>(Kp + (size_t)((J0N) + r0 + 8) * 64 + sl * 8);  \
    vrA = *reinterpret_cast<const uint4*>(Vt + (size_t)r0 * 2048 + (J0N) + sl * 8);      \
    vrB = *reinterpret_cast<const uint4*>(Vt + (size_t)(r0 + 8) * 2048 + (J0N) + sl * 8);\
  } while (0)

#define WRITE_LDS(BUF)                                                                   \
  do {                                                                                   \
    *reinterpret_cast<uint4*>((char*)&Kb[BUF][0] + sdst0)                = krA;          \
    *reinterpret_cast<uint4*>((char*)&Kb[BUF][0] + sdst0 + 8 * KP * 2)   = krB;          \
    *reinterpret_cast<uint4*>((char*)&Vb[BUF][0] + sdst0)                = vrA;          \
    *reinterpret_cast<uint4*>((char*)&Vb[BUF][0] + sdst0 + 8 * KP * 2)   = vrB;          \
  } while (0)

  // Q fragments (B-operand): qf[kc] = Q[q0+ql][kc*16 + hi*8 .. +7]  (log2e-prescaled)
  bf16x8 qf0 = *reinterpret_cast<const bf16x8*>(&Qp[(size_t)(q0 + ql) * 64 +  0 + hi * 8]);
  bf16x8 qf1 = *reinterpret_cast<const bf16x8*>(&Qp[(size_t)(q0 + ql) * 64 + 16 + hi * 8]);
  bf16x8 qf2 = *reinterpret_cast<const bf16x8*>(&Qp[(size_t)(q0 + ql) * 64 + 32 + hi * 8]);
  bf16x8 qf3 = *reinterpret_cast<const bf16x8*>(&Qp[(size_t)(q0 + ql) * 64 + 48 + hi * 8]);

  f32x16 o0 = (f32x16)0.0f, o1 = (f32x16)0.0f;  // O[d=db*32+rowpat][q=ql], db=0/1
  float m = -1e30f;                          // running max (log2 domain), identical in pair
  float lsum = 0.0f;                         // half-row sum (pair-merged in epilogue)

  ISSUE_LOADS(0);
  WRITE_LDS(0);
  __syncthreads();
  int cur = 0;

  for (int tt = 0; tt < 32; ++tt) {
    if (tt < 31) ISSUE_LOADS((tt + 1) * 64);
    const int j0 = tt * 64;

    // ---- QK^T: s0 = keys[0..31], s1 = keys[32..63] for q=ql (32x32x16, K over d)
    f32x16 s0 = (f32x16)0.0f, s1 = (f32x16)0.0f;
    {
      bf16x8 kf;
#define QK_STEP(KB, KC, QF, SACC)                                                        \
      kf = *reinterpret_cast<const bf16x8*>(&Kb[cur][((KB) * 32 + ql) * KP + (KC) * 16 + hi * 8]); \
      SACC = MFMA32(kf, QF, SACC, 0, 0, 0);
      QK_STEP(0, 0, qf0, s0) QK_STEP(0, 1, qf1, s0) QK_STEP(0, 2, qf2, s0) QK_STEP(0, 3, qf3, s0)
      QK_STEP(1, 0, qf0, s1) QK_STEP(1, 1, qf1, s1) QK_STEP(1, 2, qf2, s1) QK_STEP(1, 3, qf3, s1)
#undef QK_STEP
    }
    // ---- mask band |i-j| <= 16 (row i = q0+ql; key = j0 + kb*32 + (reg&3)+8*(reg>>2)+4*hi)
    if (j0 + 63 >= q0 - 16 && j0 <= q0 + 47) {
      const int i = q0 + ql;
#pragma unroll
      for (int reg = 0; reg < 16; ++reg) {
        int kl = (reg & 3) + 8 * (reg >> 2) + 4 * hi;
        int d0 = i - (j0 + kl);      if (d0 < 0) d0 = -d0;
        int d1 = i - (j0 + 32 + kl); if (d1 < 0) d1 = -d1;
        if (d0 <= 16) s0[reg] = -1e38f;
        if (d1 <= 16) s1[reg] = -1e38f;
      }
    }
    // ---- row-max: register tree over this lane's half + ONE pair shuffle
    f32x16 tm = __builtin_elementwise_max(s0, s1);
    float pm = fmaxf(fmaxf(fmaxf(fmaxf(tm[0], tm[1]), fmaxf(tm[2], tm[3])),
                           fmaxf(fmaxf(tm[4], tm[5]), fmaxf(tm[6], tm[7]))),
                     fmaxf(fmaxf(fmaxf(tm[8], tm[9]), fmaxf(tm[10], tm[11])),
                           fmaxf(fmaxf(tm[12], tm[13]), fmaxf(tm[14], tm[15]))));
    pm = fmaxf(pm, __shfl_xor(pm, 32));      // merge the row's two key-halves (lane pair)
    // ---- defer-max rescale (log2 units; exp2(11.54) == exp(8) bound)
    if (__any((int)(pm > m + 11.54f))) {
      float mn = fmaxf(m, pm);
      float a = hexp2(m - mn);
      m = mn;
      lsum *= a;
      o0 *= a;
      o1 *= a;
    }
    // ---- p = exp2(s-m), pack to LDS P[q][key] (stride KP); per-lane half-row partial sum
    {
      float psum = 0.0f;
      char* prow = Pw + ql * (KP * 2);
#pragma unroll
      for (int qd = 0; qd < 4; ++qd) {
        float a0 = hexp2(s0[4 * qd + 0] - m), a1 = hexp2(s0[4 * qd + 1] - m);
        float a2 = hexp2(s0[4 * qd + 2] - m), a3 = hexp2(s0[4 * qd + 3] - m);
        float b0 = hexp2(s1[4 * qd + 0] - m), b1 = hexp2(s1[4 * qd + 1] - m);
        float b2 = hexp2(s1[4 * qd + 2] - m), b3 = hexp2(s1[4 * qd + 3] - m);
        psum += ((a0 + a1) + (a2 + a3)) + ((b0 + b1) + (b2 + b3));
        uint2 pkA, pkB;
        pkA.x = cvt_pk_bf16(a0, a1); pkA.y = cvt_pk_bf16(a2, a3);
        pkB.x = cvt_pk_bf16(b0, b1); pkB.y = cvt_pk_bf16(b2, b3);
        *reinterpret_cast<uint2*>(prow + (8 * qd + 4 * hi) * 2)      = pkA;  // keys kb=0
        *reinterpret_cast<uint2*>(prow + (32 + 8 * qd + 4 * hi) * 2) = pkB;  // keys kb=1
      }
      lsum += psum;
    }
    asm volatile("s_waitcnt lgkmcnt(0)" ::: "memory");
    // ---- PV: O[db] += mfma32(Vfrag[db][s], Pfrag[s]) over 4 key-slices
#pragma unroll
    for (int s = 0; s < 4; ++s) {
      bf16x8 pf = *reinterpret_cast<const bf16x8*>(Pw + ql * (KP * 2) + (s * 16 + hi * 8) * 2);
      bf16x8 vf0 = *reinterpret_cast<const bf16x8*>(&Vb[cur][(ql) * KP + s * 16 + hi * 8]);
      bf16x8 vf1 = *reinterpret_cast<const bf16x8*>(&Vb[cur][(32 + ql) * KP + s * 16 + hi * 8]);
      o0 = MFMA32(vf0, pf, o0, 0, 0, 0);
      o1 = MFMA32(vf1, pf, o1, 0, 0, 0);
    }
    if (tt < 31) WRITE_LDS(cur ^ 1);
    __syncthreads();
    cur ^= 1;
  }

  // ---- epilogue: merge pair half-sums, normalize (lane-local), write [B,T,C] bf16
  lsum += __shfl_xor(lsum, 32);              // combine the row's two key-halves
  float inv = 1.0f / lsum;
  int b = bh >> 4, h = bh & 15;
  size_t rowoff = ((size_t)b * 2048 + q0 + ql) * 1024 + h * 64;
#pragma unroll
  for (int qd = 0; qd < 4; ++qd) {
    int d0 = 8 * qd + 4 * hi;
    uint2 pk0, pk1;
    pk0.x = cvt_pk_bf16(o0[4 * qd + 0] * inv, o0[4 * qd + 1] * inv);
    pk0.y = cvt_pk_bf16(o0[4 * qd + 2] * inv, o0[4 * qd + 3] * inv);
    pk1.x = cvt_pk_bf16(o1[4 * qd + 0] * inv, o1[4 * qd + 1] * inv);
    pk1.y = cvt_pk_bf16(o1[4 * qd + 2] * inv, o1[4 * qd + 3] * inv);
    *reinterpret_cast<uint2*>(&ab[rowoff + d0])      = pk0;
    *reinterpret_cast<uint2*>(&ab[rowoff + 32 + d0]) = pk1;
  }
#undef ISSUE_LOADS
#undef WRITE_LDS
}

// ---------------- launcher ----------------
extern "C" void kernel_launch(void* const* d_in, const int* in_sizes, int n_in,
                              void* d_out, int out_size, void* d_ws, size_t ws_size,
                              hipStream_t stream) {
  const float* x  = (const float*)d_in[0];
  const float* Wq = (const float*)d_in[1];
  const float* bq = (const float*)d_in[2];
  const float* Wk = (const float*)d_in[3];
  const float* bk = (const float*)d_in[4];
  const float* Wv = (const float*)d_in[5];
  const float* bv = (const float*)d_in[6];
  const float* Wo = (const float*)d_in[7];
  const float* bo = (const float*)d_in[8];

  u16* ws  = (u16*)d_ws;
  u16* xb  = ws;                 // 4096*1024 bf16 (reused for attention output)
  u16* wqb = ws + 4194304;
  u16* wkb = ws + 5242880;
  u16* wvb = ws + 6291456;
  u16* wob = ws + 7340032;
  u16* qbf = ws + 8388608;
  u16* kbf = ws + 12582912;
  u16* vbf = ws + 16777216;
  u16* ab  = xb;

  // fp32 -> bf16
  f2b_kernel<<<4096, 256, 0, stream>>>(x, xb, 1048576);
  f2b4_kernel<<<dim3(1024, 4), 256, 0, stream>>>(Wq, Wk, Wv, Wo, wqb, wkb, wvb, wob, 262144);

  // fused QKV projection (Q scaled 1/8*log2e, V transposed)
  gemm_qkv<<<dim3(32, 24), 256, 0, stream>>>(xb, wqb, wkb, wvb, bq, bk, bv, qbf, kbf, vbf);

  attn_kernel<<<dim3(16, 32), 256, 0, stream>>>(qbf, kbf, vbf, ab);

  gemm_out<<<dim3(32, 8), 256, 0, stream>>>(ab, wob, bo, (float*)d_out);
}

// Round 18
// 134.875 us; speedup vs baseline: 1.0720x; 1.0720x over previous
//
#include <hip/hip_runtime.h>
#include <stdint.h>

// LocalAttention: x[2,2048,1024] -> QKV proj -> anti-local attention (keep |i-j|>16) -> out proj.
// Round 18: revert attention to r15 (proven best, 64.7us; r17's 32x32 port regressed on VALU).
// + T5 s_setprio(1) around attn MFMA clusters (m191: +4-7% attn in multi-block-per-CU regime).
// + f2b/f2b4 merged into one launch (one fewer launch gap). GEMMs unchanged.

typedef unsigned short u16;
typedef short bf16x8 __attribute__((ext_vector_type(8)));
typedef float f32x4 __attribute__((ext_vector_type(4)));

#define MFMA16 __builtin_amdgcn_mfma_f32_16x16x32_bf16

__device__ __forceinline__ u16 f2bf(float f) {
  union { float f; uint32_t u; } v; v.f = f;
  return (u16)((v.u + 0x7fffu + ((v.u >> 16) & 1u)) >> 16);
}

__device__ __forceinline__ uint32_t cvt_pk_bf16(float lo, float hi) {
  uint32_t d;
  asm("v_cvt_pk_bf16_f32 %0, %1, %2" : "=v"(d) : "v"(lo), "v"(hi));
  return d;
}

// raw hardware exp2 (v_exp_f32 IS exp2 on gfx950; no libm guard code)
__device__ __forceinline__ float hexp2(float x) {
  float r;
  asm("v_exp_f32 %0, %1" : "=v"(r) : "v"(x));
  return r;
}

// ---------------- fp32 -> bf16 conversion (x + 4 weights, ONE launch) ----------------
// grid 8192 blocks x 256 threads: [0,4096) x, [4096,5120) Wq, [5120,6144) Wk,
// [6144,7168) Wv, [7168,8192) Wo.
__global__ void f2b5_kernel(const float* __restrict__ x,
                            const float* __restrict__ a, const float* __restrict__ b,
                            const float* __restrict__ c, const float* __restrict__ d,
                            u16* __restrict__ ox, u16* __restrict__ oa, u16* __restrict__ ob,
                            u16* __restrict__ oc, u16* __restrict__ od) {
  int bid = blockIdx.x;
  const float* src; u16* dst; int base;
  if (bid < 4096)      { src = x; dst = ox; base = 0; }
  else if (bid < 5120) { src = a; dst = oa; base = 4096; }
  else if (bid < 6144) { src = b; dst = ob; base = 5120; }
  else if (bid < 7168) { src = c; dst = oc; base = 6144; }
  else                 { src = d; dst = od; base = 7168; }
  int i = (bid - base) * 256 + threadIdx.x;
  float4 v = reinterpret_cast<const float4*>(src)[i];
  ushort4 o;
  o.x = f2bf(v.x); o.y = f2bf(v.y); o.z = f2bf(v.z); o.w = f2bf(v.w);
  reinterpret_cast<ushort4*>(dst)[i] = o;
}

// ---------------- shared GEMM core (padded LDS, reg-staged, NAMED registers) ----------------
#define GEMM_LOAD(REGA, REGB, A_, B_, KOFF)                                                        \
  do {                                                                                             \
    REGA##0 = *reinterpret_cast<const uint4*>(A_ + (size_t)(gm_base +  0) * 1024 + (KOFF) + sslot * 8); \
    REGA##1 = *reinterpret_cast<const uint4*>(A_ + (size_t)(gm_base + 32) * 1024 + (KOFF) + sslot * 8); \
    REGA##2 = *reinterpret_cast<const uint4*>(A_ + (size_t)(gm_base + 64) * 1024 + (KOFF) + sslot * 8); \
    REGA##3 = *reinterpret_cast<const uint4*>(A_ + (size_t)(gm_base + 96) * 1024 + (KOFF) + sslot * 8); \
    REGB##0 = *reinterpret_cast<const uint4*>(B_ + (size_t)(gn_base +  0) * 1024 + (KOFF) + sslot * 8); \
    REGB##1 = *reinterpret_cast<const uint4*>(B_ + (size_t)(gn_base + 32) * 1024 + (KOFF) + sslot * 8); \
    REGB##2 = *reinterpret_cast<const uint4*>(B_ + (size_t)(gn_base + 64) * 1024 + (KOFF) + sslot * 8); \
    REGB##3 = *reinterpret_cast<const uint4*>(B_ + (size_t)(gn_base + 96) * 1024 + (KOFF) + sslot * 8); \
  } while (0)

#define GEMM_PUBLISH()                                                                             \
  do {                                                                                             \
    *reinterpret_cast<uint4*>((char*)As + (srow +  0) * 144 + sslot * 16) = ar0;                   \
    *reinterpret_cast<uint4*>((char*)As + (srow + 32) * 144 + sslot * 16) = ar1;                   \
    *reinterpret_cast<uint4*>((char*)As + (srow + 64) * 144 + sslot * 16) = ar2;                   \
    *reinterpret_cast<uint4*>((char*)As + (srow + 96) * 144 + sslot * 16) = ar3;                   \
    *reinterpret_cast<uint4*>((char*)Bs + (srow +  0) * 144 + sslot * 16) = br0;                   \
    *reinterpret_cast<uint4*>((char*)Bs + (srow + 32) * 144 + sslot * 16) = br1;                   \
    *reinterpret_cast<uint4*>((char*)Bs + (srow + 64) * 144 + sslot * 16) = br2;                   \
    *reinterpret_cast<uint4*>((char*)Bs + (srow + 96) * 144 + sslot * 16) = br3;                   \
  } while (0)

#define GEMM_CORE(A_, B_, bm0_, bn0_)                                                              \
  constexpr int KP = 72;                                                                           \
  __shared__ __align__(16) u16 As[128 * KP];                                                       \
  __shared__ __align__(16) u16 Bs[128 * KP];                                                       \
  const int t = threadIdx.x;                                                                       \
  const int lane = t & 63;                                                                         \
  const int wv = t >> 6;                                                                           \
  const int wm = (wv >> 1) * 64;                                                                   \
  const int wn = (wv & 1) * 64;                                                                    \
  const int lg = lane >> 4;                                                                        \
  const int lr = lane & 15;                                                                        \
  const int srow = t >> 3;                                                                         \
  const int sslot = t & 7;                                                                         \
  const int gm_base = bm0_ + srow;                                                                 \
  const int gn_base = bn0_ + srow;                                                                 \
  uint4 ar0, ar1, ar2, ar3, br0, br1, br2, br3;                                                    \
  f32x4 acc[4][4];                                                                                 \
  for (int i = 0; i < 4; ++i)                                                                      \
    for (int j = 0; j < 4; ++j) acc[i][j] = (f32x4)0.0f;                                           \
  GEMM_LOAD(ar, br, A_, B_, 0);                                                                    \
  for (int k0 = 0; k0 < 1024; k0 += 64) {                                                          \
    GEMM_PUBLISH();                                                                                \
    __syncthreads();                                                                               \
    if (k0 + 64 < 1024) GEMM_LOAD(ar, br, A_, B_, k0 + 64);                                        \
    for (int kk = 0; kk < 2; ++kk) {                                                               \
      bf16x8 af[4], bfr[4];                                                                        \
      for (int i = 0; i < 4; ++i)                                                                  \
        af[i] = *reinterpret_cast<const bf16x8*>(&As[(wm + i * 16 + lr) * KP + kk * 32 + lg * 8]); \
      for (int j = 0; j < 4; ++j)                                                                  \
        bfr[j] = *reinterpret_cast<const bf16x8*>(&Bs[(wn + j * 16 + lr) * KP + kk * 32 + lg * 8]);\
      for (int i = 0; i < 4; ++i)                                                                  \
        for (int j = 0; j < 4; ++j)                                                                \
          acc[i][j] = MFMA16(af[i], bfr[j], acc[i][j], 0, 0, 0);                                   \
    }                                                                                              \
    __syncthreads();                                                                               \
  }

// ---------------- fused QKV GEMM ----------------
__global__ __launch_bounds__(256) void gemm_qkv(
    const u16* __restrict__ A,
    const u16* __restrict__ Wqb, const u16* __restrict__ Wkb, const u16* __restrict__ Wvb,
    const float* __restrict__ bqp, const float* __restrict__ bkp, const float* __restrict__ bvp,
    u16* __restrict__ qo, u16* __restrict__ ko, u16* __restrict__ vo)
{
  const int bid = blockIdx.x + gridDim.x * blockIdx.y;
  const int sid = (bid & 7) * 96 + (bid >> 3);
  const int bm0 = (sid / 24) * 128;
  const int jy = sid % 24;
  const int sel = jy >> 3;
  const int bn0 = (jy & 7) * 128;

  const u16* Bw = (sel == 0) ? Wqb : (sel == 1) ? Wkb : Wvb;
  const float* bias = (sel == 0) ? bqp : (sel == 1) ? bkp : bvp;
  // Q scale folds softmax 1/8 AND log2(e) (exp2-domain softmax downstream)
  const float scale = (sel == 0) ? 0.125f * 1.44269504f : 1.0f;

  GEMM_CORE(A, Bw, bm0, bn0)

  for (int j = 0; j < 4; ++j) {
    int gn = bn0 + wn + j * 16 + lr;
    float bv = bias[gn];
    for (int i = 0; i < 4; ++i) {
      for (int r = 0; r < 4; ++r) {
        int gm = bm0 + wm + i * 16 + lg * 4 + r;
        float val = (acc[i][j][r] + bv) * scale;
        int b = gm >> 11, tt = gm & 2047;
        int h = gn >> 6,  d = gn & 63;
        u16 o = f2bf(val);
        if (sel == 0)
          qo[((size_t)(b * 16 + h) * 2048 + tt) * 64 + d] = o;
        else if (sel == 1)
          ko[((size_t)(b * 16 + h) * 2048 + tt) * 64 + d] = o;
        else
          vo[((size_t)(b * 16 + h) * 64 + d) * 2048 + tt] = o;
      }
    }
  }
}

// ---------------- out-proj GEMM: C[M,N] fp32 = A @ W^T + bias ----------------
__global__ __launch_bounds__(256) void gemm_out(
    const u16* __restrict__ A, const u16* __restrict__ Bw,
    const float* __restrict__ bias, float* __restrict__ outp)
{
  const int bm0 = blockIdx.x * 128;
  const int bn0 = blockIdx.y * 128;

  GEMM_CORE(A, Bw, bm0, bn0)

  for (int j = 0; j < 4; ++j) {
    int gn = bn0 + wn + j * 16 + lr;
    float bv = bias[gn];
    for (int i = 0; i < 4; ++i)
      for (int r = 0; r < 4; ++r) {
        int gm = bm0 + wm + i * 16 + lg * 4 + r;
        outp[(size_t)gm * 1024 + gn] = acc[i][j][r] + bv;
      }
  }
}

// ---------------- attention (r15 proven + s_setprio around MFMA clusters) ----------------
// grid 512 blocks remapped XCD-aware. Block: 4 waves, 128 q-rows; wave owns 32 q-rows (qi=2).
// K tile [64 keys][72], V tile [64 d][72] padded LDS, dbuf, reg-staged.
// Scores in log2 domain (log2e folded into Q GEMM scale); p = v_exp_f32(s-m); deferred l-sum.
__global__ __launch_bounds__(256, 2) void attn_kernel(
    const u16* __restrict__ qb, const u16* __restrict__ kb,
    const u16* __restrict__ vtb, u16* __restrict__ ab)
{
  constexpr int KP = 72;
  __shared__ __align__(16) u16 Kb[2][64 * KP];
  __shared__ __align__(16) u16 Vb[2][64 * KP];
  __shared__ __align__(16) u16 Pl[4][32 * 64];

  const int bid = blockIdx.x + gridDim.x * blockIdx.y;
  const int sid = (bid & 7) * 64 + (bid >> 3);
  const int bx = sid & 15;
  const int bh = sid >> 4;                   // b*16+h

  const int t = threadIdx.x;
  const int lane = t & 63;
  const int wv = t >> 6;
  const int lg = lane >> 4, lr = lane & 15;
  const int q0 = bx * 128 + wv * 32;

  const u16* Qp = qb + (size_t)bh * 2048 * 64;
  const u16* Kp = kb + (size_t)bh * 2048 * 64;
  const u16* Vt = vtb + (size_t)bh * 64 * 2048;
  char* Pw = (char*)&Pl[wv][0];
  const int swz = (lr & 7) << 4;             // P-tile XOR swizzle (proven)

  const int sl = lane & 7;
  const int r0 = wv * 16 + (lane >> 3);
  const int sdst0 = r0 * (KP * 2) + sl * 16;

  uint4 krA, krB, vrA, vrB;

#define ISSUE_LOADS(J0N)                                                                 \
  do {                                                                                   \
    krA = *reinterpret_cast<const uint4*>(Kp + (size_t)((J0N) + r0) * 64 + sl * 8);      \
    krB = *reinterpret_cast<const uint4*>(Kp + (size_t)((J0N) + r0 + 8) * 64 + sl * 8);  \
    vrA = *reinterpret_cast<const uint4*>(Vt + (size_t)r0 * 2048 + (J0N) + sl * 8);      \
    vrB = *reinterpret_cast<const uint4*>(Vt + (size_t)(r0 + 8) * 2048 + (J0N) + sl * 8);\
  } while (0)

#define WRITE_LDS(BUF)                                                                   \
  do {                                                                                   \
    *reinterpret_cast<uint4*>((char*)&Kb[BUF][0] + sdst0)                = krA;          \
    *reinterpret_cast<uint4*>((char*)&Kb[BUF][0] + sdst0 + 8 * KP * 2)   = krB;          \
    *reinterpret_cast<uint4*>((char*)&Vb[BUF][0] + sdst0)                = vrA;          \
    *reinterpret_cast<uint4*>((char*)&Vb[BUF][0] + sdst0 + 8 * KP * 2)   = vrB;          \
  } while (0)

  bf16x8 qf[2][2];
  for (int qi = 0; qi < 2; ++qi)
    for (int h = 0; h < 2; ++h)
      qf[qi][h] = *reinterpret_cast<const bf16x8*>(&Qp[(size_t)(q0 + qi * 16 + lr) * 64 + h * 32 + lg * 8]);

  f32x4 o[2][4];
  for (int qi = 0; qi < 2; ++qi)
    for (int d = 0; d < 4; ++d) o[qi][d] = (f32x4)0.0f;
  float m[2] = {-1e30f, -1e30f};             // running max (log2 domain)
  float lsum[2] = {0.0f, 0.0f};              // per-lane partial sums (reduced in epilogue)

  ISSUE_LOADS(0);
  WRITE_LDS(0);
  __syncthreads();
  int cur = 0;

  for (int tt = 0; tt < 32; ++tt) {
    if (tt < 31) ISSUE_LOADS((tt + 1) * 64);
    const int j0 = tt * 64;

    // ---- QK^T (swapped): s[qi][kc] -> lane: q=q0+qi*16+lr, key=j0+kc*16+lg*4+r
    f32x4 s[2][4];
    __builtin_amdgcn_s_setprio(1);
    for (int kc = 0; kc < 4; ++kc) {
      bf16x8 kf0 = *reinterpret_cast<const bf16x8*>(&Kb[cur][(kc * 16 + lr) * KP + lg * 8]);
      bf16x8 kf1 = *reinterpret_cast<const bf16x8*>(&Kb[cur][(kc * 16 + lr) * KP + 32 + lg * 8]);
      for (int qi = 0; qi < 2; ++qi) {
        f32x4 z = (f32x4)0.0f;
        z = MFMA16(kf0, qf[qi][0], z, 0, 0, 0);
        z = MFMA16(kf1, qf[qi][1], z, 0, 0, 0);
        s[qi][kc] = z;
      }
    }
    __builtin_amdgcn_s_setprio(0);
    // ---- mask band |i-j| <= 16
    if (j0 + 63 >= q0 - 16 && j0 <= q0 + 47) {
      for (int qi = 0; qi < 2; ++qi)
        for (int kc = 0; kc < 4; ++kc)
          for (int r = 0; r < 4; ++r) {
            int i = q0 + qi * 16 + lr;
            int j = j0 + kc * 16 + lg * 4 + r;
            int dd = i - j; if (dd < 0) dd = -dd;
            if (dd <= 16) s[qi][kc][r] = -1e38f;
          }
    }
    // ---- tile row-max
    float pm[2];
    for (int qi = 0; qi < 2; ++qi) {
      f32x4 t4 = __builtin_elementwise_max(__builtin_elementwise_max(s[qi][0], s[qi][1]),
                                           __builtin_elementwise_max(s[qi][2], s[qi][3]));
      float x = fmaxf(fmaxf(t4[0], t4[1]), fmaxf(t4[2], t4[3]));
      x = fmaxf(x, __shfl_xor(x, 16));
      x = fmaxf(x, __shfl_xor(x, 32));
      pm[qi] = x;
    }
    // ---- defer-max rescale (log2 units; exp2(11.54) == exp(8) bound)
    bool need = (pm[0] > m[0] + 11.54f) || (pm[1] > m[1] + 11.54f);
    if (__any((int)need)) {
      for (int qi = 0; qi < 2; ++qi) {
        float mn = fmaxf(m[qi], pm[qi]);
        float a = hexp2(m[qi] - mn);
        m[qi] = mn;
        lsum[qi] *= a;
        for (int d = 0; d < 4; ++d) o[qi][d] *= a;
      }
    }
    // ---- p = exp2(s-m), pack to LDS; per-lane partial sum only (no shuffles)
    for (int qi = 0; qi < 2; ++qi) {
      int rowbase = (qi * 16 + lr) * 128;
      float psum = 0.0f;
      for (int kc = 0; kc < 4; ++kc) {
        float p0 = hexp2(s[qi][kc][0] - m[qi]);
        float p1 = hexp2(s[qi][kc][1] - m[qi]);
        float p2 = hexp2(s[qi][kc][2] - m[qi]);
        float p3 = hexp2(s[qi][kc][3] - m[qi]);
        psum += (p0 + p1) + (p2 + p3);
        uint2 pk;
        pk.x = cvt_pk_bf16(p0, p1);
        pk.y = cvt_pk_bf16(p2, p3);
        *reinterpret_cast<uint2*>(Pw + ((rowbase + kc * 32 + lg * 8) ^ swz)) = pk;
      }
      lsum[qi] += psum;
    }
    asm volatile("s_waitcnt lgkmcnt(0)" ::: "memory");
    // ---- PV (swapped): o[qi][d] += mfma(Vfrag, Pfrag)
    __builtin_amdgcn_s_setprio(1);
    for (int kh = 0; kh < 2; ++kh) {
      bf16x8 pa[2];
      for (int qi = 0; qi < 2; ++qi)
        pa[qi] = *reinterpret_cast<const bf16x8*>(
            Pw + (((qi * 16 + lr) * 128 + kh * 64 + lg * 16) ^ swz));
      for (int d = 0; d < 4; ++d) {
        bf16x8 vf = *reinterpret_cast<const bf16x8*>(
            &Vb[cur][(d * 16 + lr) * KP + kh * 32 + lg * 8]);
        for (int qi = 0; qi < 2; ++qi)
          o[qi][d] = MFMA16(vf, pa[qi], o[qi][d], 0, 0, 0);
      }
    }
    __builtin_amdgcn_s_setprio(0);
    if (tt < 31) WRITE_LDS(cur ^ 1);
    __syncthreads();
    cur ^= 1;
  }

  // ---- epilogue: reduce l across the 4 lanes of each row, normalize, write [B,T,C] bf16
  int b = bh >> 4, h = bh & 15;
  for (int qi = 0; qi < 2; ++qi) {
    float ls = lsum[qi];
    ls += __shfl_xor(ls, 16);
    ls += __shfl_xor(ls, 32);
    float inv = 1.0f / ls;
    size_t rowoff = ((size_t)b * 2048 + q0 + qi * 16 + lr) * 1024 + h * 64;
    for (int d = 0; d < 4; ++d) {
      uint2 pk;
      pk.x = cvt_pk_bf16(o[qi][d][0] * inv, o[qi][d][1] * inv);
      pk.y = cvt_pk_bf16(o[qi][d][2] * inv, o[qi][d][3] * inv);
      *reinterpret_cast<uint2*>(&ab[rowoff + d * 16 + lg * 4]) = pk;
    }
  }
#undef ISSUE_LOADS
#undef WRITE_LDS
}

// ---------------- launcher ----------------
extern "C" void kernel_launch(void* const* d_in, const int* in_sizes, int n_in,
                              void* d_out, int out_size, void* d_ws, size_t ws_size,
                              hipStream_t stream) {
  const float* x  = (const float*)d_in[0];
  const float* Wq = (const float*)d_in[1];
  const float* bq = (const float*)d_in[2];
  const float* Wk = (const float*)d_in[3];
  const float* bk = (const float*)d_in[4];
  const float* Wv = (const float*)d_in[5];
  const float* bv = (const float*)d_in[6];
  const float* Wo = (const float*)d_in[7];
  const float* bo = (const float*)d_in[8];

  u16* ws  = (u16*)d_ws;
  u16* xb  = ws;                 // 4096*1024 bf16 (reused for attention output)
  u16* wqb = ws + 4194304;
  u16* wkb = ws + 5242880;
  u16* wvb = ws + 6291456;
  u16* wob = ws + 7340032;
  u16* qbf = ws + 8388608;
  u16* kbf = ws + 12582912;
  u16* vbf = ws + 16777216;
  u16* ab  = xb;

  // fp32 -> bf16 (x + all four weights, one launch)
  f2b5_kernel<<<8192, 256, 0, stream>>>(x, Wq, Wk, Wv, Wo, xb, wqb, wkb, wvb, wob);

  // fused QKV projection (Q scaled 1/8*log2e, V transposed)
  gemm_qkv<<<dim3(32, 24), 256, 0, stream>>>(xb, wqb, wkb, wvb, bq, bk, bv, qbf, kbf, vbf);

  attn_kernel<<<dim3(16, 32), 256, 0, stream>>>(qbf, kbf, vbf, ab);

  gemm_out<<<dim3(32, 8), 256, 0, stream>>>(ab, wob, bo, (float*)d_out);
}